// Round 3
// baseline (141.540 us; speedup 1.0000x reference)
//
#include <hip/hip_runtime.h>
#include <stdint.h>

// ContrastiveLoss (SimCLR NT-Xent), B=4096, D=128, T=0.5
// loss = (1/2B) * sum_k log(denom_k)  -  (1/(B*T)) * sum_i dot(z_i, z_j_i)

#define TEMP 0.5f
// exp(x/T) = exp2(x * log2(e)/T); T=0.5 -> scale = 2*log2(e)
#define EXP2_SCALE 2.885390081777927f

typedef __bf16 bf16_t;
typedef bf16_t bf16x8 __attribute__((ext_vector_type(8)));
typedef float floatx4 __attribute__((ext_vector_type(4)));

__device__ __forceinline__ unsigned short f32_to_bf16(float f) {
    union { float f; uint32_t u; } v; v.f = f;
    uint32_t u = v.u;
    uint32_t r = (u + 0x7FFFu + ((u >> 16) & 1u)) >> 16;  // RNE
    return (unsigned short)r;
}

__device__ __forceinline__ bf16x8 as_bf16x8(uint4 v) {
    union { uint4 u; bf16x8 b; } c; c.u = v; return c.b;
}

// ---------------------------------------------------------------------------
// Kernel 1: per-row L2 normalize -> bf16 reps[2B][128]; pos[i] = dot(z_i,z_j)
// in exact fp32 (plain store, no atomics). Also zeroes rowsum[] (8 floats per
// block x 1024 blocks) so the separate memset dispatch is gone.
// ---------------------------------------------------------------------------
__global__ __launch_bounds__(256) void norm_pos_kernel(
        const float* __restrict__ p1, const float* __restrict__ p2,
        unsigned short* __restrict__ reps, float* __restrict__ pos,
        float* __restrict__ rowsum, int B) {
    if (threadIdx.x < 8) rowsum[blockIdx.x * 8 + threadIdx.x] = 0.f;

    int wave = threadIdx.x >> 6;
    int lane = threadIdx.x & 63;
    int i = blockIdx.x * 4 + wave;
    if (i >= B) return;

    const float2* r1 = (const float2*)(p1 + (size_t)i * 128);
    const float2* r2 = (const float2*)(p2 + (size_t)i * 128);
    float2 a = r1[lane];
    float2 b = r2[lane];
    float ss1 = a.x * a.x + a.y * a.y;
    float ss2 = b.x * b.x + b.y * b.y;
    float d   = a.x * b.x + a.y * b.y;
    #pragma unroll
    for (int off = 32; off > 0; off >>= 1) {
        ss1 += __shfl_xor(ss1, off);
        ss2 += __shfl_xor(ss2, off);
        d   += __shfl_xor(d,   off);
    }
    float rn1 = rsqrtf(fmaxf(ss1, 1e-24f));
    float rn2 = rsqrtf(fmaxf(ss2, 1e-24f));

    ushort2* z1 = (ushort2*)reps + (size_t)i * 64;
    ushort2* z2 = (ushort2*)reps + (size_t)(B + i) * 64;
    z1[lane] = make_ushort2(f32_to_bf16(a.x * rn1), f32_to_bf16(a.y * rn1));
    z2[lane] = make_ushort2(f32_to_bf16(b.x * rn2), f32_to_bf16(b.y * rn2));

    if (lane == 0) pos[i] = d * rn1 * rn2;
}

// ---------------------------------------------------------------------------
// Kernel 2: sim+exp, LDS-free. R3 restructure for concurrency: wave owns
// 2 row-tiles (32 rows, A-frags in 32 VGPRs), block = 4 waves = 128-row panel
// x 256-col strip. Grid (32,64) = 2048 blocks = 8192 waves = 8 waves/SIMD of
// work (R2 had only 4 -> latency-bound at 20% occupancy). B-frags from global
// (reps 2 MB, L1/L2-resident; 4 waves/block share via L1), explicitly
// double-buffered in registers so the compiler can overlap the next gather
// with current MFMAs. Diagonal mask hoisted to a wave-uniform branch.
// ---------------------------------------------------------------------------
__global__ __launch_bounds__(256) void simexp_kernel(
        const unsigned short* __restrict__ reps,
        float* __restrict__ rowsum) {
    const int tid  = threadIdx.x;
    const int wave = tid >> 6;
    const int lane = tid & 63;
    const int quad = lane >> 4;
    const int l16  = lane & 15;

    const int rowWave = blockIdx.y * 128 + wave * 32;  // this wave's 32 rows
    const int colBase = blockIdx.x * 256;              // block's col strip

    const uint4* g = (const uint4*)reps;  // 16 uint4 per 256-B row

    // A-fragments: 2 row-tiles x 4 k-steps (32 VGPRs)
    bf16x8 a[2][4];
    #pragma unroll
    for (int t = 0; t < 2; ++t)
        #pragma unroll
        for (int ks = 0; ks < 4; ++ks)
            a[t][ks] = as_bf16x8(g[(size_t)(rowWave + t * 16 + l16) * 16 + ks * 4 + quad]);

    float rs[2][4];
    #pragma unroll
    for (int t = 0; t < 2; ++t)
        #pragma unroll
        for (int r = 0; r < 4; ++r) rs[t][r] = 0.f;

    // does this block's panel touch the diagonal?
    const bool diagBlock = (blockIdx.y * 128 < colBase + 256) &&
                           (colBase < blockIdx.y * 128 + 128);

    // register double-buffer for B-frags
    bf16x8 b[2][4];
    #pragma unroll
    for (int ks = 0; ks < 4; ++ks)
        b[0][ks] = as_bf16x8(g[(size_t)(colBase + l16) * 16 + ks * 4 + quad]);

    #pragma unroll
    for (int ctile = 0; ctile < 16; ++ctile) {
        const int cur = ctile & 1;
        if (ctile < 15) {
            const int colT = colBase + (ctile + 1) * 16;
            #pragma unroll
            for (int ks = 0; ks < 4; ++ks)
                b[cur ^ 1][ks] = as_bf16x8(g[(size_t)(colT + l16) * 16 + ks * 4 + quad]);
        }

        floatx4 acc[2];
        #pragma unroll
        for (int t = 0; t < 2; ++t) acc[t] = (floatx4){0.f, 0.f, 0.f, 0.f};

        #pragma unroll
        for (int ks = 0; ks < 4; ++ks)
            #pragma unroll
            for (int t = 0; t < 2; ++t)
                acc[t] = __builtin_amdgcn_mfma_f32_16x16x32_bf16(a[t][ks], b[cur][ks], acc[t], 0, 0, 0);

        const int c = colBase + ctile * 16 + l16;  // this lane's output column
        if (diagBlock) {
            #pragma unroll
            for (int t = 0; t < 2; ++t)
                #pragma unroll
                for (int reg = 0; reg < 4; ++reg) {
                    int r = rowWave + t * 16 + quad * 4 + reg;
                    float e = (r == c) ? 0.f : exp2f(acc[t][reg] * EXP2_SCALE);
                    rs[t][reg] += e;
                }
        } else {
            #pragma unroll
            for (int t = 0; t < 2; ++t)
                #pragma unroll
                for (int reg = 0; reg < 4; ++reg)
                    rs[t][reg] += exp2f(acc[t][reg] * EXP2_SCALE);
        }
    }

    // reduce across the 16 columns (l16 lanes) of each quad
    #pragma unroll
    for (int off = 1; off < 16; off <<= 1)
        #pragma unroll
        for (int t = 0; t < 2; ++t)
            #pragma unroll
            for (int reg = 0; reg < 4; ++reg)
                rs[t][reg] += __shfl_xor(rs[t][reg], off);

    if (l16 == 0) {
        #pragma unroll
        for (int t = 0; t < 2; ++t)
            #pragma unroll
            for (int reg = 0; reg < 4; ++reg)
                atomicAdd(&rowsum[rowWave + t * 16 + quad * 4 + reg], rs[t][reg]);
    }
}

// ---------------------------------------------------------------------------
// Kernel 3: single block; out[0] = mean(log(rowsum)) - sum(pos)/(B*T).
// ---------------------------------------------------------------------------
__global__ __launch_bounds__(1024) void finalize_kernel(
        const float* __restrict__ rowsum, const float* __restrict__ pos,
        float* __restrict__ out, int N2, int B) {
    float v = 0.f;
    for (int k = threadIdx.x; k < N2; k += 1024) v += logf(rowsum[k]);
    float p = 0.f;
    for (int i = threadIdx.x; i < B; i += 1024) p += pos[i];
    float local = v * (1.0f / (float)N2) - p * (1.0f / ((float)B * TEMP));

    #pragma unroll
    for (int off = 32; off > 0; off >>= 1) local += __shfl_xor(local, off);

    __shared__ float wsum[16];
    int wave = threadIdx.x >> 6, lane = threadIdx.x & 63;
    if (lane == 0) wsum[wave] = local;
    __syncthreads();
    if (threadIdx.x == 0) {
        float s = 0.f;
        for (int i = 0; i < 16; ++i) s += wsum[i];
        out[0] = s;
    }
}

extern "C" void kernel_launch(void* const* d_in, const int* in_sizes, int n_in,
                              void* d_out, int out_size, void* d_ws, size_t ws_size,
                              hipStream_t stream) {
    const float* p1 = (const float*)d_in[0];
    const float* p2 = (const float*)d_in[1];
    float* out = (float*)d_out;

    const int B  = in_sizes[0] / 128;   // 4096
    const int N2 = 2 * B;               // 8192

    // ws layout: [reps bf16: N2*256 B][rowsum fp32: N2*4 B][pos fp32: B*4 B]
    unsigned short* reps = (unsigned short*)d_ws;
    float* rowsum = (float*)((char*)d_ws + (size_t)N2 * 256);
    float* pos    = rowsum + N2;

    norm_pos_kernel<<<dim3((B + 3) / 4), dim3(256), 0, stream>>>(p1, p2, reps, pos, rowsum, B);

    dim3 grid(N2 / 256, N2 / 128);  // 32 x 64 = 2048 blocks, 8192 waves
    simexp_kernel<<<grid, dim3(256), 0, stream>>>(reps, rowsum);

    finalize_kernel<<<dim3(1), dim3(1024), 0, stream>>>(rowsum, pos, out, N2, B);
}